// Round 4
// baseline (690.579 us; speedup 1.0000x reference)
//
#include <hip/hip_runtime.h>
#include <stdint.h>

#define B_  4
#define S_  2048
#define H_  16
#define DH_ 64
#define DM_ 1024

typedef __attribute__((ext_vector_type(8))) short bf16x8;  // 8 bf16 = 4 VGPR
typedef __attribute__((ext_vector_type(4))) float f32x4;

// lgkm-only barrier: orders LDS traffic but leaves global (vmcnt) loads in
// flight across the barrier -- __syncthreads() would drain vmcnt(0) and
// defeat register prefetch.
#define BAR() asm volatile("s_waitcnt lgkmcnt(0)\n\ts_barrier" ::: "memory")

__device__ __forceinline__ ushort f2bf(float x){
  uint32_t u = __float_as_uint(x);
  u += 0x7FFFu + ((u >> 16) & 1u);   // RNE
  return (ushort)(u >> 16);
}
__device__ __forceinline__ uint32_t pack2(float a, float b){
  return (uint32_t)f2bf(a) | ((uint32_t)f2bf(b) << 16);
}
// truncating bf16 pack (P in [0,1]): 1 v_perm_b32
__device__ __forceinline__ uint32_t packtr(float a, float b){
  return __builtin_amdgcn_perm(__float_as_uint(b), __float_as_uint(a), 0x07060302u);
}
__device__ __forceinline__ f32x4 zero4(){ f32x4 z; z.x=0.f;z.y=0.f;z.z=0.f;z.w=0.f; return z; }

// ---------------------------------------------------------------------------
// W [K][N] fp32 -> Wt [N][K] bf16 (transpose + convert), 3 weights batched.
// ---------------------------------------------------------------------------
__global__ __launch_bounds__(256) void wtrans3(const float* __restrict__ Wq,
                                               const float* __restrict__ Wk,
                                               const float* __restrict__ Wv,
                                               ushort* __restrict__ Tq,
                                               ushort* __restrict__ Tk,
                                               ushort* __restrict__ Tv){
  const float* W = (blockIdx.z==0) ? Wq : (blockIdx.z==1) ? Wk : Wv;
  ushort* Wt     = (blockIdx.z==0) ? Tq : (blockIdx.z==1) ? Tk : Tv;
  __shared__ __align__(16) float t[32][33];
  int n0 = blockIdx.x * 32, k0 = blockIdx.y * 32;
  int col = threadIdx.x & 31, rg = threadIdx.x >> 5;
  #pragma unroll
  for (int i = 0; i < 4; i++){
    int r = rg + i*8;
    t[r][col] = W[(size_t)(k0 + r) * DM_ + n0 + col];
  }
  __syncthreads();
  #pragma unroll
  for (int i = 0; i < 4; i++){
    int r = rg + i*8;
    Wt[(size_t)(n0 + r) * DM_ + k0 + col] = f2bf(t[col][r]);
  }
}

// ---------------------------------------------------------------------------
// QKV projection, one dispatch (z: 0=Q,1=K,2=V), 128x128 tile, BK=64.
// fp32 X staged via registers (bf16 pack at ds_write), double-buffered LDS,
// ONE lgkm-only barrier per 64-k tile: next tile's global loads stay in
// flight across it (ping-pong register sets, 2 LDS buffers).
// z<2: D = Wt * X^T -> out[B,H,S,D];  z==2: D = X * Wt^T -> Vt[B,H,D,S]
// ---------------------------------------------------------------------------
__device__ __forceinline__ void stage_load(const float* xrow, const ushort* wrow, int k0,
                                           float4 (&xs)[8], uint4 (&ws)[4]){
  #pragma unroll
  for (int j=0;j<8;j++) xs[j] = *(const float4*)(xrow + k0 + j*4);
  #pragma unroll
  for (int j=0;j<4;j++) ws[j] = *(const uint4*)(wrow + k0 + j*8);
}
__device__ __forceinline__ void stage_write(ushort* lx, ushort* lw, int rr, int koff,
                                            const float4 (&xs)[8], const uint4 (&ws)[4]){
  #pragma unroll
  for (int j=0;j<4;j++){
    int c = (koff>>3) + j;
    int slot = c ^ (rr & 7);
    uint4 p;
    p.x = pack2(xs[2*j].x,   xs[2*j].y);   p.y = pack2(xs[2*j].z,   xs[2*j].w);
    p.z = pack2(xs[2*j+1].x, xs[2*j+1].y); p.w = pack2(xs[2*j+1].z, xs[2*j+1].w);
    *(uint4*)&lx[rr*64 + slot*8] = p;
    *(uint4*)&lw[rr*64 + slot*8] = ws[j];
  }
}
__device__ __forceinline__ void compute64(const ushort* aS, const ushort* bS,
                                          int wm, int wn, int ln, int lq,
                                          f32x4 (&acc)[4][4]){
  #pragma unroll
  for (int ks=0; ks<2; ks++){
    bf16x8 af[4], bfr[4];
    #pragma unroll
    for (int i=0;i<4;i++){
      int ar = wm*64 + i*16 + ln;
      int g = ks*4 + lq;
      af[i] = *(const bf16x8*)&aS[ar*64 + (g ^ (ar&7))*8];
    }
    #pragma unroll
    for (int j=0;j<4;j++){
      int br = wn*64 + j*16 + ln;
      int g = ks*4 + lq;
      bfr[j] = *(const bf16x8*)&bS[br*64 + (g ^ (br&7))*8];
    }
    #pragma unroll
    for (int i=0;i<4;i++)
      #pragma unroll
      for (int j=0;j<4;j++)
        acc[i][j] = __builtin_amdgcn_mfma_f32_16x16x32_bf16(af[i], bfr[j], acc[i][j], 0,0,0);
  }
}

__global__ __launch_bounds__(256, 2) void gemm_qkv(
    const float* __restrict__ Xq, const float* __restrict__ Xk, const float* __restrict__ Xv,
    const ushort* __restrict__ Wtq, const ushort* __restrict__ Wtk, const ushort* __restrict__ Wtv,
    const float* __restrict__ bq, const float* __restrict__ bk, const float* __restrict__ bv,
    ushort* __restrict__ Qo, ushort* __restrict__ Ko, ushort* __restrict__ Vo)
{
  int z = blockIdx.z;
  const float*  X   = (z==0)?Xq :(z==1)?Xk :Xv;
  const ushort* Wt  = (z==0)?Wtq:(z==1)?Wtk:Wtv;
  const float*  bias= (z==0)?bq :(z==1)?bk :bv;
  ushort*       out = (z==0)?Qo :(z==1)?Ko :Vo;

  __shared__ __align__(16) ushort lw[2][128*64];
  __shared__ __align__(16) ushort lx[2][128*64];

  int tid = threadIdx.x, l = tid & 63, w = tid >> 6;
  int ln = l & 15, lq = l >> 4;
  int sbase = blockIdx.x * 128, fbase = blockIdx.y * 128;
  int wm = w >> 1, wn = w & 1;
  int rr = tid >> 1, koff = (tid & 1) * 32;

  const float*  xrow = X  + (size_t)(sbase + rr)*DM_ + koff;
  const ushort* wrow = Wt + (size_t)(fbase + rr)*DM_ + koff;

  f32x4 acc[4][4];
  #pragma unroll
  for (int i=0;i<4;i++)
    #pragma unroll
    for(int j=0;j<4;j++) acc[i][j] = zero4();

  float4 xa[8], xb[8]; uint4 wa[4], wb[4];
  stage_load(xrow, wrow, 0, xa, wa);

  for (int k0 = 0; k0 < DM_; k0 += 128){
    stage_load(xrow, wrow, k0 + 64, xb, wb);           // in flight across BAR
    stage_write(lx[0], lw[0], rr, koff, xa, wa);       // waits only xa/wa
    BAR();
    if (z < 2) compute64(lw[0], lx[0], wm, wn, ln, lq, acc);
    else       compute64(lx[0], lw[0], wm, wn, ln, lq, acc);
    if (k0 + 128 < DM_) stage_load(xrow, wrow, k0 + 128, xa, wa);
    stage_write(lx[1], lw[1], rr, koff, xb, wb);
    BAR();
    if (z < 2) compute64(lw[1], lx[1], wm, wn, ln, lq, acc);
    else       compute64(lx[1], lw[1], wm, wn, ln, lq, acc);
  }

  if (z < 2){
    // D[m=feature][n=row]; col=ln -> s, row=lq*4+r -> f
    #pragma unroll
    for (int i=0;i<4;i++){
      int fr = fbase + wm*64 + i*16 + (lq<<2);
      float4 bv4 = *(const float4*)&bias[fr];
      int h = fr >> 6, d0 = fr & 63;
      #pragma unroll
      for (int j=0;j<4;j++){
        int s = sbase + wn*64 + j*16 + ln;
        int b = s >> 11, sq = s & 2047;
        f32x4 v = acc[i][j];
        uint2 pk;
        pk.x = pack2(v.x + bv4.x, v.y + bv4.y);
        pk.y = pack2(v.z + bv4.z, v.w + bv4.w);
        *(uint2*)&out[(((size_t)(b*H_ + h))*S_ + sq)*DH_ + d0] = pk;
      }
    }
  } else {
    // D[m=row][n=feature]; col=ln -> f, row=lq*4+r -> s  => Vt[b,h,d,s]
    #pragma unroll
    for (int j=0;j<4;j++){
      int fc = fbase + wn*64 + j*16 + ln;
      float bv1 = bias[fc];
      int h = fc >> 6, d = fc & 63;
      #pragma unroll
      for (int i=0;i<4;i++){
        int s = sbase + wm*64 + i*16 + (lq<<2);
        int b = s >> 11, sq = s & 2047;
        f32x4 v = acc[i][j];
        uint2 pk;
        pk.x = pack2(v.x + bv1, v.y + bv1);
        pk.y = pack2(v.z + bv1, v.w + bv1);
        *(uint2*)&out[(((size_t)(b*H_ + h))*DH_ + d)*S_ + sq] = pk;
      }
    }
  }
}

// ---------------------------------------------------------------------------
// Fused attention, q-tile 32, 1024 blocks, wave = batch in MFMA phases.
// lgkm-only barriers: register prefetches (V this-iter, K next-iter, mask
// next-iter) survive the barrier. Issue order V -> K -> mask so each
// consumer's vmcnt wait leaves younger prefetches outstanding.
// ---------------------------------------------------------------------------
__global__ __launch_bounds__(256, 4) void attn(
    const ushort* __restrict__ Q, const ushort* __restrict__ K,
    const ushort* __restrict__ Vt, const float* __restrict__ mask,
    float* __restrict__ out)
{
  __shared__ __align__(16) float  Sl[B_*32*32];   // 16 KB
  __shared__ __align__(16) ushort Pl[B_*32*32];   // 8 KB
  int tid = threadIdx.x;
  int l = tid & 63, w = tid >> 6;        // w = batch
  int ln = l & 15, lq = l >> 4;

  int fid = blockIdx.x;
  int xcd = fid & 7, slot = fid >> 3;
  int h = slot & 15;
  int qt = (slot >> 4) * 8 + xcd;
  int q0 = qt * 32;

  const ushort* Qbh = Q  + (((size_t)(w*H_ + h))*S_ + q0)*DH_;
  const ushort* Kbh = K  + ((size_t)(w*H_ + h))*S_*DH_;
  const ushort* Vbh = Vt + ((size_t)(w*H_ + h))*DH_*S_;

  bf16x8 qf[2][2];
  #pragma unroll
  for (int q2=0;q2<2;q2++)
    #pragma unroll
    for (int ks=0;ks<2;ks++)
      qf[q2][ks] = *(const bf16x8*)&Qbh[(size_t)(q2*16 + ln)*DH_ + ks*32 + lq*8];

  f32x4 of[4][2];
  #pragma unroll
  for (int i=0;i<4;i++)
    #pragma unroll
    for(int j=0;j<2;j++) of[i][j] = zero4();

  int q_sm = w*8 + (l >> 3);
  int kc2  = l & 7;
  const float* mrow = mask + (size_t)(q0 + q_sm)*S_ + kc2*4;

  bf16x8 kf[2][2];
  float4 mk[4];
  #pragma unroll
  for (int t=0;t<2;t++)
    #pragma unroll
    for (int ks=0;ks<2;ks++)
      kf[t][ks] = *(const bf16x8*)&Kbh[(size_t)(t*16 + ln)*DH_ + ks*32 + lq*8];
  #pragma unroll
  for (int b2=0;b2<4;b2++)
    mk[b2] = *(const float4*)(mrow + (size_t)b2*S_*S_);

  for (int kk = 0; kk < S_; kk += 32){
    int kn = (kk + 32) & (S_ - 1);

    // ---- S^T = K * Q^T (kf prefetched last iter) ----
    f32x4 sacc[2][2];
    #pragma unroll
    for (int t=0;t<2;t++)
      #pragma unroll
      for (int q2=0;q2<2;q2++){
        f32x4 a = __builtin_amdgcn_mfma_f32_16x16x32_bf16(kf[t][0], qf[q2][0], zero4(), 0,0,0);
        sacc[t][q2] = __builtin_amdgcn_mfma_f32_16x16x32_bf16(kf[t][1], qf[q2][1], a, 0,0,0);
      }
    #pragma unroll
    for (int t=0;t<2;t++)
      #pragma unroll
      for (int q2=0;q2<2;q2++){
        int q = q2*16 + ln;
        *(f32x4*)&Sl[w*1024 + q*32 + ((t*4 + lq) ^ (q & 7))*4] = sacc[t][q2];
      }
    BAR();

    // ---- prefetch: V (this iter), K (next iter) ----
    bf16x8 vf[4];
    #pragma unroll
    for (int dt=0;dt<4;dt++)
      vf[dt] = *(const bf16x8*)&Vbh[(size_t)(dt*16 + ln)*S_ + kk + lq*8];
    #pragma unroll
    for (int t=0;t<2;t++)
      #pragma unroll
      for (int ks=0;ks<2;ks++)
        kf[t][ks] = *(const bf16x8*)&Kbh[(size_t)(kn + t*16 + ln)*DH_ + ks*32 + lq*8];

    // ---- softmax over batch (mask mk[] prefetched last iter) ----
    f32x4 sr[4];
    #pragma unroll
    for (int b2=0;b2<4;b2++)
      sr[b2] = *(const f32x4*)&Sl[b2*1024 + q_sm*32 + (kc2 ^ (q_sm & 7))*4];
    float p[4][4];
    #pragma unroll
    for (int j=0;j<4;j++){
      float s0 = __builtin_fmaf(sr[0][j], 0.125f, __fmul_rn(((const float*)&mk[0])[j], -1e9f));
      float s1 = __builtin_fmaf(sr[1][j], 0.125f, __fmul_rn(((const float*)&mk[1])[j], -1e9f));
      float s2 = __builtin_fmaf(sr[2][j], 0.125f, __fmul_rn(((const float*)&mk[2])[j], -1e9f));
      float s3 = __builtin_fmaf(sr[3][j], 0.125f, __fmul_rn(((const float*)&mk[3])[j], -1e9f));
      float mx = fmaxf(fmaxf(s0,s1), fmaxf(s2,s3));
      float e0 = __expf(s0-mx), e1 = __expf(s1-mx);
      float e2 = __expf(s2-mx), e3 = __expf(s3-mx);
      float inv = __builtin_amdgcn_rcpf((e0+e1)+(e2+e3));
      p[0][j]=e0*inv; p[1][j]=e1*inv; p[2][j]=e2*inv; p[3][j]=e3*inv;
    }
    // ---- prefetch mask (next iter) ----
    #pragma unroll
    for (int b2=0;b2<4;b2++)
      mk[b2] = *(const float4*)(mrow + (size_t)b2*S_*S_ + kn);
    #pragma unroll
    for (int b2=0;b2<4;b2++){
      uint2 pk;
      pk.x = packtr(p[b2][0], p[b2][1]);
      pk.y = packtr(p[b2][2], p[b2][3]);
      *(uint2*)((char*)Pl + b2*2048 + q_sm*64 + kc2*8) = pk;
    }
    BAR();

    // ---- O^T += V^T * P^T ----
    bf16x8 pf[2];
    #pragma unroll
    for (int q2=0;q2<2;q2++)
      pf[q2] = *(const bf16x8*)((char*)Pl + w*2048 + (q2*16 + ln)*64 + lq*16);
    #pragma unroll
    for (int dt=0;dt<4;dt++)
      #pragma unroll
      for (int q2=0;q2<2;q2++)
        of[dt][q2] = __builtin_amdgcn_mfma_f32_16x16x32_bf16(vf[dt], pf[q2], of[dt][q2], 0,0,0);
  }

  #pragma unroll
  for (int q2=0;q2<2;q2++){
    float* ob = out + ((size_t)w*S_ + q0 + q2*16 + ln)*DM_ + h*DH_;
    #pragma unroll
    for (int dt=0;dt<4;dt++)
      *(f32x4*)&ob[dt*16 + lq*4] = of[dt][q2];
  }
}

// ---------------------------------------------------------------------------
extern "C" void kernel_launch(void* const* d_in, const int* in_sizes, int n_in,
                              void* d_out, int out_size, void* d_ws, size_t ws_size,
                              hipStream_t stream)
{
  const float* xq   = (const float*)d_in[0];
  const float* xk   = (const float*)d_in[1];
  const float* xv   = (const float*)d_in[2];
  const float* mask = (const float*)d_in[3];
  const float* Wq   = (const float*)d_in[4];
  const float* bq   = (const float*)d_in[5];
  const float* Wk   = (const float*)d_in[6];
  const float* bk   = (const float*)d_in[7];
  const float* Wv   = (const float*)d_in[8];
  const float* bv   = (const float*)d_in[9];
  float* out = (float*)d_out;

  char* ws = (char*)d_ws;                      // 54 MB used
  ushort* Wtq = (ushort*)(ws);                 // 2 MB each
  ushort* Wtk = (ushort*)(ws + (2ull<<20));
  ushort* Wtv = (ushort*)(ws + (4ull<<20));
  ushort* Qb  = (ushort*)(ws + (6ull<<20));    // 16 MB each
  ushort* Kb  = (ushort*)(ws + (22ull<<20));
  ushort* Vtb = (ushort*)(ws + (38ull<<20));

  wtrans3<<<dim3(32,32,3), 256, 0, stream>>>(Wq, Wk, Wv, Wtq, Wtk, Wtv);
  gemm_qkv<<<dim3(64,8,3), 256, 0, stream>>>(xq, xk, xv, Wtq, Wtk, Wtv,
                                             bq, bk, bv, Qb, Kb, Vtb);
  attn<<<1024, 256, 0, stream>>>(Qb, Kb, Vtb, mask, out);
}